// Round 11
// baseline (185.107 us; speedup 1.0000x reference)
//
#include <hip/hip_runtime.h>
#include <cstdint>
#include <cstddef>

// SLSTM cell, B=4096 IN=1024 HID=2048 GATE=8192, NH=8 HS=256.
// v12 = v11 with a CORRECT hand-simulated vmcnt ledger:
//  per tile: issue {ALO,AHI}@P1 + WAITV(4); issue {BLO,BHI}@P2; WAITV(2)@P4.
//  Every half-tile read is preceded (cross-wave, via barrier) by a wait that
//  retired it. Prologue: 4 halves + WAITV(2)+BAR. Contiguous WtX B-slab;
//  WtH for hproj. hproj = v10 stage-all. prep/casts unchanged.

typedef unsigned short u16;
typedef unsigned int   u32;
typedef __bf16 bf16x8 __attribute__((ext_vector_type(8)));
typedef float  f32x4  __attribute__((ext_vector_type(4)));

__device__ __forceinline__ u16 f2bf(float f) {
  u32 u = __builtin_bit_cast(u32, f);
  u32 r = (u + 0x7fffu + ((u >> 16) & 1u)) >> 16;   // RNE
  return (u16)r;
}
__device__ __forceinline__ float bf2f(u16 v) {
  u32 u = ((u32)v) << 16;
  return __builtin_bit_cast(float, u);
}
__device__ __forceinline__ void gll16(const void* g, void* l) {
  __builtin_amdgcn_global_load_lds(
      (__attribute__((address_space(1))) void*)(uintptr_t)g,
      (__attribute__((address_space(3))) void*)l, 16, 0, 0);
}

#define BAR() asm volatile("s_barrier" ::: "memory")
#define WAITV(N) asm volatile("s_waitcnt vmcnt(" #N ")" ::: "memory")

// ---------------- cast f32 -> bf16, 8 elems/thread ----------------
__global__ void cast_bf16_kernel(const float* __restrict__ src, u16* __restrict__ dst, int n8) {
  int i = blockIdx.x * blockDim.x + threadIdx.x;
  if (i >= n8) return;
  const float4* s = reinterpret_cast<const float4*>(src) + (size_t)i * 2;
  float4 a = s[0], b = s[1];
  union { u16 h[8]; uint4 v; } o;
  o.h[0] = f2bf(a.x); o.h[1] = f2bf(a.y); o.h[2] = f2bf(a.z); o.h[3] = f2bf(a.w);
  o.h[4] = f2bf(b.x); o.h[5] = f2bf(b.y); o.h[6] = f2bf(b.z); o.h[7] = f2bf(b.w);
  reinterpret_cast<uint4*>(dst)[i] = o.v;
}

// ---------------- pack W: WtX [jb][q][jj][k<1024], WtH [g][k-1024] ----------------
__global__ void pack_w_kernel(const float* __restrict__ Wi, const float* __restrict__ Wh,
                              u16* __restrict__ WtX, u16* __restrict__ WtH) {
  __shared__ u16 tile[64][65];
  const int g0 = blockIdx.x * 64;
  const int r0 = blockIdx.y * 64;
  const int tx = threadIdx.x;
  const int ty = threadIdx.y;
  #pragma unroll
  for (int i = 0; i < 4; ++i) {
    const int rr = ty + 16 * i;
    const int r = r0 + rr;
    const int g = g0 + tx;
    float v;
    if (r < 1024) v = Wi[(size_t)r * 8192 + g];
    else {
      const int head = g >> 10;
      v = Wh[(size_t)(head * 256 + (r - 1024)) * 1024 + (g & 1023)];
    }
    tile[rr][tx] = f2bf(v);
  }
  __syncthreads();
  #pragma unroll
  for (int i = 0; i < 4; ++i) {
    const int gg = ty + 16 * i;
    const int g = g0 + gg;
    const int r = r0 + tx;
    if (r0 < 1024) {
      const int jb = (g & 2047) >> 6, q = g >> 11, jj = g & 63;
      WtX[(size_t)((jb * 4 + q) * 64 + jj) * 1024 + r] = tile[tx][gg];
    } else {
      WtH[(size_t)g * 256 + (r - 1024)] = tile[tx][gg];
    }
  }
}

// ---------------- hproj (v10 stage-all): hp[b][g] = sum_k h[b,head*256+k] WtH[g][k]
__global__ __launch_bounds__(512, 1) void hproj_kernel(
    const u16* __restrict__ hb, const u16* __restrict__ WtH, u16* __restrict__ hp)
{
  extern __shared__ __align__(16) u16 lds[];
  const int tid = threadIdx.x, lane = tid & 63, w = tid >> 6;
  const int wr = w >> 2, wc = w & 3;
  const int d = blockIdx.x;
  const int xcd = d & 7, loc = d >> 3;
  const int rb = (xcd & 3) * 8 + (loc & 7);     // 0..31
  const int cb = (xcd >> 2) * 32 + (loc >> 3);  // 0..63
  const int row0 = rb * 128;
  const int g0 = cb * 128;
  const int head = cb >> 3;
  const int l15 = lane & 15, l4 = lane >> 4;
  const int sw = (l4 ^ ((l15 >> 1) & 3)) << 3;

  #pragma unroll
  for (int i = 0; i < 8; ++i) {
    const int u = i * 512 + tid;
    const int kk = u >> 9, rem = u & 511;
    const int row = rem >> 2, ch = rem & 3;
    const int chs = ch ^ ((row >> 1) & 3);
    gll16(hb + (size_t)(row0 + row) * 2048 + head * 256 + kk * 32 + chs * 8,
          lds + u * 8);
    gll16(WtH + (size_t)(g0 + row) * 256 + kk * 32 + chs * 8,
          lds + 32768 + u * 8);
  }
  WAITV(0); BAR();

  f32x4 acc[2][4];
  #pragma unroll
  for (int q = 0; q < 2; ++q)
    #pragma unroll
    for (int f = 0; f < 4; ++f)
      acc[q][f] = f32x4{0.0f, 0.0f, 0.0f, 0.0f};

  #pragma unroll
  for (int kk = 0; kk < 8; ++kk) {
    bf16x8 av[4], bv[2];
    #pragma unroll
    for (int f = 0; f < 4; ++f)
      av[f] = *(const bf16x8*)(lds + kk * 4096 + (wr * 64 + f * 16 + l15) * 32 + sw);
    #pragma unroll
    for (int q = 0; q < 2; ++q)
      bv[q] = *(const bf16x8*)(lds + 32768 + kk * 4096 + (wc * 32 + q * 16 + l15) * 32 + sw);
    #pragma unroll
    for (int q = 0; q < 2; ++q)
      #pragma unroll
      for (int f = 0; f < 4; ++f)
        acc[q][f] = __builtin_amdgcn_mfma_f32_16x16x32_bf16(av[f], bv[q], acc[q][f], 0, 0, 0);
  }

  #pragma unroll
  for (int q = 0; q < 2; ++q)
    #pragma unroll
    for (int f = 0; f < 4; ++f)
      #pragma unroll
      for (int r = 0; r < 4; ++r) {
        const int row = row0 + wr * 64 + f * 16 + l4 * 4 + r;
        const int g = g0 + wc * 32 + q * 16 + l15;
        hp[(size_t)row * 8192 + g] = f2bf(acc[q][f][r]);
      }
}

// ---------------- main: x-GEMM (K=1024) + gates, hp added in epilogue ----------------
__global__ __launch_bounds__(512, 2) void slstm_main(
    const u16* __restrict__ xb, const u16* __restrict__ WtX, const u16* __restrict__ hp,
    const float* __restrict__ b_i, const float* __restrict__ b_h,
    const float* __restrict__ c_in, const float* __restrict__ m_in, const float* __restrict__ n_in,
    float* __restrict__ out)
{
  extern __shared__ __align__(16) u16 lds[];
  const int tid = threadIdx.x, lane = tid & 63, w = tid >> 6;
  const int wr = w >> 2, wj = w & 3;
  const int d = blockIdx.x;
  const int xcd = d & 7, loc = d >> 3;
  const int row_blk = (xcd & 3) * 4 + (loc & 3);   // 0..15
  const int j_blk   = (xcd >> 2) * 16 + (loc >> 2);// 0..31
  const int row0 = row_blk * 256;
  const int j0   = j_blk * 64;
  const int l15 = lane & 15, l4 = lane >> 4;
  const int sl0 = (l4 ^ (l15 & 7)) * 8;
  const int sl1 = ((4 + l4) ^ (l15 & 7)) * 8;
  const int aBase = l15 * 64;
  const int bBase = wj * 1024 + l15 * 64;

  // biases first; drain before ledger starts
  const int gj = j0 + wj * 16 + l15;
  const float bias0 = b_i[gj]        + b_h[gj];
  const float bias1 = b_i[2048 + gj] + b_h[2048 + gj];
  const float bias2 = b_i[4096 + gj] + b_h[4096 + gj];
  const float bias3 = b_i[6144 + gj] + b_h[6144 + gj];
  WAITV(0);

  const int u0 = tid, u1 = 512 + tid;
  const int r0u = u0 >> 3, r1u = u1 >> 3;
  const int kc0 = (u0 & 7) ^ (r0u & 7), kc1 = (u1 & 7) ^ (r1u & 7);
  const int d0 = u0 * 8, d1 = u1 * 8;
  const size_t aL0 = (size_t)(row0 + r0u) * 1024 + kc0 * 8;
  const size_t aL1 = (size_t)(row0 + r1u) * 1024 + kc1 * 8;
  // contiguous B slab for this block: WtX + jb*256*1024
  const u16* Wb = WtX + (size_t)j_blk * 262144;
  const size_t bL0 = (size_t)r0u * 1024 + kc0 * 8;           // gate0 cols
  const size_t bL1 = (size_t)r1u * 1024 + kc1 * 8;           // gate1 cols
  const size_t bH0 = (size_t)(128 + r0u) * 1024 + kc0 * 8;   // gate2
  const size_t bH1 = (size_t)(128 + r1u) * 1024 + kc1 * 8;   // gate3

  f32x4 acc[4][8];
  #pragma unroll
  for (int q = 0; q < 4; ++q)
    #pragma unroll
    for (int f = 0; f < 8; ++f)
      acc[q][f] = f32x4{0.0f, 0.0f, 0.0f, 0.0f};

  // epilogue staging constants
  const int esStripe = tid >> 8, esRowq = (tid >> 4) & 15, esCol16 = tid & 15;
  const size_t esC0 = (size_t)(row0 + esStripe * 128 + esRowq) * 2048 + j0 + esCol16 * 4;
  const int hu0 = tid, hu1 = 512 + tid;
  const size_t esH0 = (size_t)(row0 + ((hu0 >> 7) & 1) * 128 + ((hu0 >> 3) & 15)) * 8192
                      + (hu0 >> 8) * 2048 + j0 + (hu0 & 7) * 8;
  const size_t esH1 = (size_t)(row0 + ((hu1 >> 7) & 1) * 128 + ((hu1 >> 3) & 15)) * 8192
                      + (hu1 >> 8) * 2048 + j0 + (hu1 & 7) * 8;
  const int dH0 = hu0 * 8, dH1 = hu1 * 8;
  const int dC = tid * 8;

#define X_ALO(T, NB) do { gll16(xb + aL0 + (size_t)(T)*64, lds + (NB)*16384 + d0); \
                          gll16(xb + aL1 + (size_t)(T)*64, lds + (NB)*16384 + d1); } while(0)
#define X_AHI(T, NB) do { gll16(xb + aL0 + (size_t)128*1024 + (size_t)(T)*64, lds + (NB)*16384 + 8192 + d0); \
                          gll16(xb + aL1 + (size_t)128*1024 + (size_t)(T)*64, lds + (NB)*16384 + 8192 + d1); } while(0)
#define X_BLO(T, NB) do { gll16(Wb + bL0 + (size_t)(T)*64, lds + 32768 + (NB)*16384 + d0); \
                          gll16(Wb + bL1 + (size_t)(T)*64, lds + 32768 + (NB)*16384 + d1); } while(0)
#define X_BHI(T, NB) do { gll16(Wb + bH0 + (size_t)(T)*64, lds + 32768 + (NB)*16384 + 8192 + d0); \
                          gll16(Wb + bH1 + (size_t)(T)*64, lds + 32768 + (NB)*16384 + 8192 + d1); } while(0)

// A read: half = wr (rows wr*128..+128), slot-in-half = FH*64 + f_*16 + l15
#define RD_A(DST, BUF, FH) do { \
  _Pragma("unroll") for (int f_ = 0; f_ < 4; ++f_) { \
    const u16* p_ = lds + (BUF)*16384 + wr*8192 + (FH)*4096 + aBase + f_*1024; \
    DST[f_][0] = *(const bf16x8*)(p_ + sl0); \
    DST[f_][1] = *(const bf16x8*)(p_ + sl1); } } while(0)
#define RD_B(DST, BUF, QH) do { \
  _Pragma("unroll") for (int q_ = 0; q_ < 2; ++q_) { \
    const u16* p_ = lds + 32768 + (BUF)*16384 + (QH)*8192 + q_*4096 + bBase; \
    DST[q_][0] = *(const bf16x8*)(p_ + sl0); \
    DST[q_][1] = *(const bf16x8*)(p_ + sl1); } } while(0)
#define MMQ(FH, QH, AF, BF) do { \
  __builtin_amdgcn_s_setprio(1); \
  _Pragma("unroll") for (int q_ = 0; q_ < 2; ++q_) \
  _Pragma("unroll") for (int f_ = 0; f_ < 4; ++f_) \
  _Pragma("unroll") for (int k_ = 0; k_ < 2; ++k_) \
    acc[(QH)*2+q_][(FH)*4+f_] = __builtin_amdgcn_mfma_f32_16x16x32_bf16( \
        AF[f_][k_], BF[q_][k_], acc[(QH)*2+q_][(FH)*4+f_], 0, 0, 0); \
  __builtin_amdgcn_s_setprio(0); } while(0)

// K-tile, verified ledger: issue {ALO,AHI}@P1 + W(4); {BLO,BHI}@P2; W(2)@P4.
// P1 reads {ALO,AHI,BLO}_t  (retired by prev tile's P4 W(2)+BAR)
// P2 reads {BHI}_t          (retired by this tile's P1 W(4)+BAR)
#define TILE(BUF, NB, TN) do { \
  bf16x8 aF[4][2], aG[4][2], bF[2][2], bG[2][2]; \
  RD_A(aF, BUF, 0); RD_B(bF, BUF, 0); \
  X_ALO(TN, NB); X_AHI(TN, NB); WAITV(4); BAR(); \
  MMQ(0, 0, aF, bF); \
  RD_B(bG, BUF, 1); \
  X_BLO(TN, NB); X_BHI(TN, NB); BAR(); \
  MMQ(0, 1, aF, bG); \
  RD_A(aG, BUF, 1); \
  BAR(); \
  MMQ(1, 1, aG, bG); \
  WAITV(2); BAR(); \
  MMQ(1, 0, aG, bF); } while(0)

  // ES chunk staging (parity regions overlaid on GEMM buffers)
#define ISSUE_ES(K) do { const int p_ = (K)&1; \
  const int cb_ = p_ ? 16384 : 0; const int hb_ = p_ ? 49152 : 32768; \
  gll16(c_in + esC0 + (size_t)(K)*32768, lds + cb_ + dC); \
  gll16(m_in + esC0 + (size_t)(K)*32768, lds + cb_ + 4096 + dC); \
  gll16(n_in + esC0 + (size_t)(K)*32768, lds + cb_ + 8192 + dC); \
  gll16(hp + esH0 + (size_t)(K)*131072, lds + hb_ + dH0); \
  gll16(hp + esH1 + (size_t)(K)*131072, lds + hb_ + dH1); } while(0)

  // ---- prologue: tile0's 4 halves; retire {ALO,AHI,BLO} before tile0 ----
  X_ALO(0, 0); X_AHI(0, 0); X_BLO(0, 0); X_BHI(0, 0);
  WAITV(2); BAR();

  // ---- tiles 0..13 (steady ledger), tile14 stages t=15 ----
  for (int tt = 0; tt < 7; ++tt) {
    TILE(0, 1, 2 * tt + 1);
    TILE(1, 0, 2 * tt + 2);
  }
  TILE(0, 1, 15);

  // ---- tile 15 (buf1): ES chunk0 staged in the issue slots ----
  {
    bf16x8 aF[4][2], aG[4][2], bF[2][2], bG[2][2];
    RD_A(aF, 1, 0); RD_B(bF, 1, 0);
    gll16(c_in + esC0, lds + dC);                  // ES: c,m,n
    gll16(m_in + esC0, lds + 4096 + dC);
    gll16(n_in + esC0, lds + 8192 + dC);
    WAITV(3); BAR();                               // retires BHI15
    MMQ(0, 0, aF, bF);
    RD_B(bG, 1, 1);
    gll16(hp + esH0, lds + 32768 + dH0);           // ES: hp
    gll16(hp + esH1, lds + 32768 + dH1);
    BAR();
    MMQ(0, 1, aF, bG);
    RD_A(aG, 1, 1);
    BAR();
    MMQ(1, 1, aG, bG);
    BAR();
    MMQ(1, 0, aG, bF);
  }

  // ---- epilogue: 8 pipelined chunks ----
#define ECOMP(K) do { const int p_ = (K)&1; \
  const float* pc_ = (const float*)(lds + (p_ ? 16384 : 0)); \
  const float* pm_ = pc_ + 2048; \
  const float* pn_ = pc_ + 4096; \
  const u16* ph_ = lds + (p_ ? 49152 : 32768); \
  _Pragma("unroll") for (int r_ = 0; r_ < 4; ++r_) { \
    const int fx_ = wr * 1024 + (l4 * 4 + r_) * 64 + wj * 16 + l15; \
    const float cv = pc_[fx_], mv = pm_[fx_], nv = pn_[fx_]; \
    const float it = acc[0][K][r_] + bias0 + bf2f(ph_[fx_]); \
    const float ft = acc[1][K][r_] + bias1 + bf2f(ph_[2048 + fx_]); \
    const float zt = acc[2][K][r_] + bias2 + bf2f(ph_[4096 + fx_]); \
    const float ot = acc[3][K][r_] + bias3 + bf2f(ph_[6144 + fx_]); \
    const float mn = fmaxf(ft + mv, it); \
    const float iv = __expf(it - mn); \
    const float fv = __expf(ft - mn + mv); \
    const float az = fabsf(zt); \
    const float e2 = __expf(-2.0f * az); \
    const float tz = (1.0f - e2) / (1.0f + e2); \
    const float zv = (zt >= 0.0f) ? tz : -tz; \
    const float ov = 1.0f / (1.0f + __expf(-ot)); \
    const float cn = fv * cv + iv * zv; \
    const float nn = fv * nv + iv; \
    const float hn = ov * (cn / nn); \
    const int gb = row0 + wr * 128 + (K) * 16 + l4 * 4 + r_; \
    const size_t idx = (size_t)gb * 2048 + gj; \
    out[idx]            = hn; \
    out[ 8388608 + idx] = cn; \
    out[16777216 + idx] = mn; \
    out[25165824 + idx] = nn; \
  } } while(0)

  WAITV(0); BAR();
  #pragma unroll
  for (int k = 0; k < 8; ++k) {
    if (k < 7) ISSUE_ES(k + 1);
    ECOMP(k);
    if (k < 7) { WAITV(0); BAR(); }
  }
#undef X_ALO
#undef X_AHI
#undef X_BLO
#undef X_BHI
#undef RD_A
#undef RD_B
#undef MMQ
#undef TILE
#undef ISSUE_ES
#undef ECOMP
}

extern "C" void kernel_launch(void* const* d_in, const int* in_sizes, int n_in,
                              void* d_out, int out_size, void* d_ws, size_t ws_size,
                              hipStream_t stream) {
  (void)in_sizes; (void)n_in; (void)out_size; (void)ws_size;
  const float* x  = (const float*)d_in[0];
  const float* h  = (const float*)d_in[1];
  const float* c  = (const float*)d_in[2];
  const float* m  = (const float*)d_in[3];
  const float* n  = (const float*)d_in[4];
  const float* Wi = (const float*)d_in[5];
  const float* bi = (const float*)d_in[6];
  const float* Wh = (const float*)d_in[7];
  const float* bh = (const float*)d_in[8];
  float* out = (float*)d_out;

  // workspace (bf16): WtX 8192x1024 | WtH 8192x256 | xb 4096x1024 | hb 4096x2048 | hp 4096x8192
  u16* WtX = (u16*)d_ws;
  u16* WtH = WtX + (size_t)8192 * 1024;
  u16* xb  = WtH + (size_t)8192 * 256;
  u16* hb  = xb + (size_t)4096 * 1024;
  u16* hp  = hb + (size_t)4096 * 2048;

  hipFuncSetAttribute((const void*)hproj_kernel,
                      hipFuncAttributeMaxDynamicSharedMemorySize, 131072);
  hipFuncSetAttribute((const void*)slstm_main,
                      hipFuncAttributeMaxDynamicSharedMemorySize, 131072);

  cast_bf16_kernel<<<2048, 256, 0, stream>>>(x, xb, 4096 * 1024 / 8);
  cast_bf16_kernel<<<4096, 256, 0, stream>>>(h, hb, 4096 * 2048 / 8);
  pack_w_kernel<<<dim3(128, 20), dim3(64, 16), 0, stream>>>(Wi, Wh, WtX, WtH);
  hproj_kernel<<<2048, 512, 131072, stream>>>(hb, WtH, hp);
  slstm_main<<<512, 512, 131072, stream>>>(xb, WtX, hp, bi, bh, c, m, n, out);
}